// Round 7
// baseline (1154.974 us; speedup 1.0000x reference)
//
#include <hip/hip_runtime.h>
#include <hip/hip_bf16.h>

// AUGRU dynamic RNN: B=1024, T=512, D=128.
// Round-7: TWO-GROUP INTERLEAVE. 32 blocks x 512 threads; block owns 32
// batch rows = two independent 16-row groups A,B. B runs half a step behind:
// each barrier interval = {one group's MFMA phase} + {other group's
// trans/update phase}, so MFMA overlaps sigmoid/tanh/LDS across groups
// within each wave's in-order stream (phases were previously homogeneous ->
// ~1200 cyc/step of pure phase serialization). Barriers per logical step
// halve. Per-group math byte-identical to R6 (587.6us): R5 x-partial
// pipelining, cvt_pk_bf16, folded biases, lgkm-only barriers. x-buffer now
// single per group (read/write on opposite barrier sides). LDS 60.3KB.

#define Bn 1024
#define Tn 512
#define Dn 128

typedef __attribute__((ext_vector_type(8))) short short8;   // 8 bf16 (4 VGPR)
typedef __attribute__((ext_vector_type(4))) float f32x4;

#define HS 132   // f32 LDS row stride (floats)
#define BS 136   // bf16 LDS row stride (shorts): 272 B = 17*16B

#define NL2E  (-1.4426950408889634f)   // -log2(e)
#define N2L2E (-2.8853900817779268f)   // -2*log2(e)

__device__ __forceinline__ short f2bf(float f) {            // cold paths only
    __hip_bfloat16 h = __float2bfloat16(f);   // RNE
    return __builtin_bit_cast(short, h);
}
__device__ __forceinline__ unsigned cvt_pk_bf16(float a, float b) {
    unsigned r;
    asm("v_cvt_pk_bf16_f32 %0, %1, %2" : "=v"(r) : "v"(a), "v"(b));
    return r;
}
// LDS-only barrier: order LDS ops across waves WITHOUT draining vmcnt.
__device__ __forceinline__ void barrier_lds() {
    __builtin_amdgcn_sched_barrier(0);
    asm volatile("s_waitcnt lgkmcnt(0)" ::: "memory");
    __builtin_amdgcn_s_barrier();
    __builtin_amdgcn_sched_barrier(0);
}

#define MFMA_(a, b, c) __builtin_amdgcn_mfma_f32_16x16x32_bf16((a), (b), (c), 0, 0, 0)

__launch_bounds__(512, 2)
__global__ void augru_kernel(const float* __restrict__ X,    // [B,T,D]
                             const float* __restrict__ ATT,  // [B,T,1]
                             const float* __restrict__ GK,   // [256,256]
                             const float* __restrict__ GB,   // [256]
                             const float* __restrict__ CK,   // [256,128]
                             const float* __restrict__ CB,   // [128]
                             const int*   __restrict__ SL,   // [B,1]
                             float* __restrict__ OUT) {      // [B,T,D]
    __shared__ short hbA [16 * BS], hbB [16 * BS];   // h bf16 mirrors
    __shared__ short rhbA[16 * BS], rhbB[16 * BS];   // r*h bf16
    __shared__ short xbA [16 * BS], xbB [16 * BS];   // x tile (single buf)
    __shared__ float hfA [16 * HS], hfB [16 * HS];   // master h f32
    __shared__ float ubA [16 * HS], ubB [16 * HS];   // u' f32
    __shared__ float abufA[2][16], abufB[2][16];
    __shared__ int   lenbufA[16], lenbufB[16];

    const int tid  = threadIdx.x;
    const int wid  = tid >> 6;          // 0..7
    const int lane = tid & 63;
    const int lm   = lane & 15;
    const int q    = lane >> 4;
    const int b0A  = blockIdx.x * 32;
    const int b0B  = b0A + 16;

    // ---------- preload weight B-frags (shared by both groups) ----------
    short8 fgx[2][4], fgh[2][4], fcx[4], fch[4];
    const int gcolb = 32 * wid + lm;
    const int ccol  = 16 * wid + lm;
#pragma unroll
    for (int ns = 0; ns < 2; ++ns) {
        const int col = gcolb + 16 * ns;
#pragma unroll
        for (int ks = 0; ks < 4; ++ks) {
            short8 vx, vh;
#pragma unroll
            for (int j = 0; j < 8; ++j) {
                const int k = ks * 32 + q * 8 + j;
                vx[j] = f2bf(GK[k * 256 + col]);
                vh[j] = f2bf(GK[(128 + k) * 256 + col]);
            }
            fgx[ns][ks] = vx; fgh[ns][ks] = vh;
        }
    }
#pragma unroll
    for (int ks = 0; ks < 4; ++ks) {
        short8 vx, vh;
#pragma unroll
        for (int j = 0; j < 8; ++j) {
            const int k = ks * 32 + q * 8 + j;
            vx[j] = f2bf(CK[k * 128 + ccol]);
            vh[j] = f2bf(CK[(128 + k) * 128 + ccol]);
        }
        fcx[ks] = vx; fch[ks] = vh;
    }
    const float pb0 = GB[gcolb]      * NL2E;
    const float pb1 = GB[gcolb + 16] * NL2E;
    const float cbp = CB[ccol]       * N2L2E;

    // ---------- init LDS ----------
    for (int i = tid; i < 16 * HS; i += 512) { hfA[i] = 0.0f; hfB[i] = 0.0f; }
    for (int i = tid; i < 16 * BS; i += 512) { hbA[i] = 0;    hbB[i] = 0;    }
    if (tid < 16) {
        lenbufA[tid]  = SL[b0A + tid];
        lenbufB[tid]  = SL[b0B + tid];
        abufA[0][tid] = ATT[(size_t)(b0A + tid) * Tn];
        abufB[0][tid] = ATT[(size_t)(b0B + tid) * Tn];
    }
    const int prow = tid >> 5;
    const int pcol = (tid & 31) * 4;

#define STAGE_X(XBg, B0g, tt) {                                                     \
        float4 v_ = *(const float4*)(X + ((size_t)((B0g) + prow) * Tn + (tt)) * Dn + pcol); \
        uint2 pp_; pp_.x = cvt_pk_bf16(v_.x, v_.y); pp_.y = cvt_pk_bf16(v_.z, v_.w); \
        *(uint2*)&XBg[prow * BS + pcol] = pp_; }

    STAGE_X(xbA, b0A, 0)
    STAGE_X(xbB, b0B, 0)
    __syncthreads();

    int lenA_i[4], lenB_i[4];
#pragma unroll
    for (int i = 0; i < 4; ++i) { lenA_i[i] = lenbufA[q * 4 + i]; lenB_i[i] = lenbufB[q * 4 + i]; }

    // ---------- prologue: x-partials for step 0 (both groups) ----------
    f32x4 gxA0 = {0,0,0,0}, gxA1 = {0,0,0,0}, cxA = {0,0,0,0};
    f32x4 gxB0 = {0,0,0,0}, gxB1 = {0,0,0,0}, cxB = {0,0,0,0};
    f32x4 ccA, ccB, g0A, g1A, g0B, g1B;
    float4 xpreA, xpreB; float apreA, apreB;
    {
        short8 fa[4], fb[4];
#pragma unroll
        for (int ks = 0; ks < 4; ++ks) {
            fa[ks] = *(const short8*)&xbA[lm * BS + ks * 32 + q * 8];
            fb[ks] = *(const short8*)&xbB[lm * BS + ks * 32 + q * 8];
        }
#pragma unroll
        for (int ks = 0; ks < 4; ++ks) {
            gxA0 = MFMA_(fa[ks], fgx[0][ks], gxA0);
            gxA1 = MFMA_(fa[ks], fgx[1][ks], gxA1);
            cxA  = MFMA_(fa[ks], fcx[ks],  cxA);
            gxB0 = MFMA_(fb[ks], fgx[0][ks], gxB0);
            gxB1 = MFMA_(fb[ks], fgx[1][ks], gxB1);
            cxB  = MFMA_(fb[ks], fcx[ks],  cxB);
        }
    }
    __syncthreads();
    STAGE_X(xbA, b0A, 1)
    STAGE_X(xbB, b0B, 1)
    __syncthreads();

    // ---------- phase macros (each group's math identical to R6) ----------
#define P1MFMA(HBg, XBg, GX0, GX1, CXg, CCg, G0, G1, XPREg, APREg, B0g, t)          \
    {                                                                               \
        const int tp1 = ((t) + 1 < Tn) ? (t) + 1 : Tn - 1;                          \
        const int tp2 = ((t) + 2 < Tn) ? (t) + 2 : Tn - 1;                          \
        XPREg = *(const float4*)(X + ((size_t)((B0g) + prow) * Tn + tp2) * Dn + pcol); \
        APREg = (tid < 16) ? ATT[(size_t)((B0g) + tid) * Tn + tp1] : 0.0f;          \
        short8 axn[4], ah[4];                                                       \
        _Pragma("unroll")                                                           \
        for (int ks = 0; ks < 4; ++ks) {                                            \
            axn[ks] = *(const short8*)&XBg[lm * BS + ks * 32 + q * 8];              \
            ah[ks]  = *(const short8*)&HBg[lm * BS + ks * 32 + q * 8];              \
        }                                                                           \
        G0 = GX0; G1 = GX1; CCg = CXg;                                              \
        f32x4 n0 = {0,0,0,0}, n1 = {0,0,0,0}, n2 = {0,0,0,0};                       \
        _Pragma("unroll")                                                           \
        for (int ks = 0; ks < 4; ++ks) {                                            \
            G0 = MFMA_(ah[ks], fgh[0][ks], G0);                                     \
            G1 = MFMA_(ah[ks], fgh[1][ks], G1);                                     \
            n0 = MFMA_(axn[ks], fgx[0][ks], n0);                                    \
            n1 = MFMA_(axn[ks], fgx[1][ks], n1);                                    \
            n2 = MFMA_(axn[ks], fcx[ks],  n2);                                      \
        }                                                                           \
        GX0 = n0; GX1 = n1; CXg = n2;                                               \
    }

#define ACT(RHBg, UBg, HFg, ABUFg, G0, G1, t)                                       \
    {                                                                               \
        if (wid < 4) {            /* r cols */                                      \
            const int col0 = 32 * wid + lm;                                         \
            _Pragma("unroll")                                                       \
            for (int i = 0; i < 4; ++i) {                                           \
                const int row = q * 4 + i;                                          \
                const float e0 = __builtin_amdgcn_exp2f(fmaf(G0[i], NL2E, pb0));    \
                const float e1 = __builtin_amdgcn_exp2f(fmaf(G1[i], NL2E, pb1));    \
                const float rh0 = __builtin_amdgcn_rcpf(1.0f + e0) * HFg[row * HS + col0];      \
                const float rh1 = __builtin_amdgcn_rcpf(1.0f + e1) * HFg[row * HS + col0 + 16]; \
                const unsigned p = cvt_pk_bf16(rh0, rh1);                           \
                RHBg[row * BS + col0]      = (short)p;                              \
                RHBg[row * BS + col0 + 16] = (short)(p >> 16);                      \
            }                                                                       \
        } else {                  /* u cols */                                      \
            const int cu0 = 32 * (wid - 4) + lm;                                    \
            float am[4];                                                            \
            _Pragma("unroll")                                                       \
            for (int i = 0; i < 4; ++i) am[i] = 1.0f - ABUFg[(t) & 1][q * 4 + i];   \
            _Pragma("unroll")                                                       \
            for (int i = 0; i < 4; ++i) {                                           \
                const int row = q * 4 + i;                                          \
                const float e0 = __builtin_amdgcn_exp2f(fmaf(G0[i], NL2E, pb0));    \
                const float e1 = __builtin_amdgcn_exp2f(fmaf(G1[i], NL2E, pb1));    \
                UBg[row * HS + cu0]      = am[i] * __builtin_amdgcn_rcpf(1.0f + e0); \
                UBg[row * HS + cu0 + 16] = am[i] * __builtin_amdgcn_rcpf(1.0f + e1); \
            }                                                                       \
        }                                                                           \
    }

#define P2MFMA(RHBg, CCg)                                                           \
    {                                                                               \
        _Pragma("unroll")                                                           \
        for (int ks = 0; ks < 4; ++ks) {                                            \
            short8 arh = *(const short8*)&RHBg[lm * BS + ks * 32 + q * 8];          \
            CCg = MFMA_(arh, fch[ks], CCg);                                         \
        }                                                                           \
    }

#define UPD(HBg, XBg, HFg, UBg, ABUFg, LEN, CCg, XPREg, APREg, B0g, t)              \
    {                                                                               \
        float hxv[4];                                                               \
        _Pragma("unroll")                                                           \
        for (int i = 0; i < 4; ++i) {                                               \
            const int row = q * 4 + i;                                              \
            const float e  = __builtin_amdgcn_exp2f(fmaf(CCg[i], N2L2E, cbp));      \
            const float cv = fmaf(2.0f, __builtin_amdgcn_rcpf(1.0f + e), -1.0f);    \
            const float up   = UBg[row * HS + ccol];                                \
            const float hold = HFg[row * HS + ccol];                                \
            const float hn   = fmaf(up, hold - cv, cv);                             \
            const bool valid = ((t) < LEN[i]);                                      \
            const float hnext = valid ? hn : hold;                                  \
            OUT[((size_t)((B0g) + row) * Tn + (t)) * Dn + ccol] = valid ? hn : 0.0f; \
            HFg[row * HS + ccol] = hnext;                                           \
            hxv[i] = hnext;                                                         \
        }                                                                           \
        {                                                                           \
            const unsigned pA_ = cvt_pk_bf16(hxv[0], hxv[1]);                       \
            const unsigned pB_ = cvt_pk_bf16(hxv[2], hxv[3]);                       \
            HBg[(q * 4 + 0) * BS + ccol] = (short)pA_;                              \
            HBg[(q * 4 + 1) * BS + ccol] = (short)(pA_ >> 16);                      \
            HBg[(q * 4 + 2) * BS + ccol] = (short)pB_;                              \
            HBg[(q * 4 + 3) * BS + ccol] = (short)(pB_ >> 16);                      \
        }                                                                           \
        {                                                                           \
            uint2 pp_;                                                              \
            pp_.x = cvt_pk_bf16(XPREg.x, XPREg.y);                                  \
            pp_.y = cvt_pk_bf16(XPREg.z, XPREg.w);                                  \
            *(uint2*)&XBg[prow * BS + pcol] = pp_;                                  \
            if (tid < 16) ABUFg[((t) + 1) & 1][tid] = APREg;                        \
        }                                                                           \
    }

    // ---------- B head-start: PH1 of step 0 ----------
    P1MFMA(hbB, xbB, gxB0, gxB1, cxB, ccB, g0B, g1B, xpreB, apreB, b0B, 0)
    ACT(rhbB, ubB, hfB, abufB, g0B, g1B, 0)
    barrier_lds();

    // ---------- time loop: iter t does A-step t and B-steps t/t+1 halves ----
    for (int t = 0; t < Tn; ++t) {
        // interval 1: A.PH1(t)  ||  B.PH2(t)
        P1MFMA(hbA, xbA, gxA0, gxA1, cxA, ccA, g0A, g1A, xpreA, apreA, b0A, t)
        P2MFMA(rhbB, ccB)
        ACT(rhbA, ubA, hfA, abufA, g0A, g1A, t)
        UPD(hbB, xbB, hfB, ubB, abufB, lenB_i, ccB, xpreB, apreB, b0B, t)
        barrier_lds();
        // interval 2: A.PH2(t)  ||  B.PH1(t+1)
        P2MFMA(rhbA, ccA)
        P1MFMA(hbB, xbB, gxB0, gxB1, cxB, ccB, g0B, g1B, xpreB, apreB, b0B, t + 1)
        UPD(hbA, xbA, hfA, ubA, abufA, lenA_i, ccA, xpreA, apreA, b0A, t)
        ACT(rhbB, ubB, hfB, abufB, g0B, g1B, t + 1)
        barrier_lds();
    }
#undef P1MFMA
#undef ACT
#undef P2MFMA
#undef UPD
#undef STAGE_X
}

extern "C" void kernel_launch(void* const* d_in, const int* in_sizes, int n_in,
                              void* d_out, int out_size, void* d_ws, size_t ws_size,
                              hipStream_t stream) {
    (void)in_sizes; (void)n_in; (void)d_ws; (void)ws_size; (void)out_size;
    const float* X   = (const float*)d_in[0];
    const float* ATT = (const float*)d_in[1];
    const float* GK  = (const float*)d_in[2];
    const float* GB  = (const float*)d_in[3];
    const float* CK  = (const float*)d_in[4];
    const float* CB  = (const float*)d_in[5];
    const int*   SL  = (const int*)d_in[6];
    float* OUT = (float*)d_out;

    augru_kernel<<<dim3(Bn / 32), dim3(512), 0, stream>>>(X, ATT, GK, GB, CK, CB, SL, OUT);
}